// Round 3
// baseline (463.437 us; speedup 1.0000x reference)
//
#include <hip/hip_runtime.h>

// Problem constants (match reference)
#define BB 4
#define SS 4096
#define DM 4096
#define DF 512
#define LN_EPS 1e-5f
#define NORM_EPS 1e-12f
#define SNR 0.3f   // TARGET_SNR * CONFIDENCE * INERTIA

// Workspace layout (float offsets)
#define WS_PROJ  0        // B*DM = 16384 floats
#define WS_PSUM  16384    // B*256 per-wave |proj|^2 partials
#define WS_RMS   17408    // B floats
#define WS_LAST  17412    // B ints (int view)

__device__ __forceinline__ float block_reduce_sum(float v, float* sm) {
    // 256 threads = 4 waves of 64
    for (int off = 32; off > 0; off >>= 1) v += __shfl_down(v, off, 64);
    int wid = threadIdx.x >> 6, lane = threadIdx.x & 63;
    __syncthreads();                 // protect sm from previous reduction
    if (lane == 0) sm[wid] = v;
    __syncthreads();
    return sm[0] + sm[1] + sm[2] + sm[3];
}

// Front kernel (260 blocks):
//   blocks 0..3   : last[r] = max(1,sum(mask))-1 ; rms of x[r,last,:]
//   blocks 4..259 : 64 blocks per batch row. Each block redundantly computes
//                   the DF=512 LayerNorm for its row into LDS (identical
//                   result in every block -> no cross-block dependency), then
//                   its 4 waves compute 16 proj dots each + |proj|^2 partials.
__global__ __launch_bounds__(256) void k_front(const float* __restrict__ x,
                                               const float* __restrict__ ff,
                                               const int*   __restrict__ mask,
                                               const float* __restrict__ gamma,
                                               const float* __restrict__ beta,
                                               const float* __restrict__ W,
                                               const float* __restrict__ bvec,
                                               float* __restrict__ ws) {
    __shared__ float sm[4];
    __shared__ float hsh[DF];
    const int b = blockIdx.x, tid = threadIdx.x;

    if (b < BB) {
        const int r = b;
        // last[r]  (exact: mask sum <= 4096 representable in float)
        int ms = 0;
        for (int i = tid; i < SS; i += 256) ms += mask[r * SS + i];
        float msum = block_reduce_sum((float)ms, sm);
        int last = max(1, (int)(msum + 0.5f)) - 1;
        // RMS of x[r, last, :]
        const float4* xr = (const float4*)(x + ((size_t)r * SS + (size_t)last) * DM);
        float ss = 0.0f;
        for (int i = tid; i < DM / 4; i += 256) {
            float4 v = xr[i];
            ss += v.x * v.x + v.y * v.y + v.z * v.z + v.w * v.w;
        }
        ss = block_reduce_sum(ss, sm);
        if (tid == 0) {
            ws[WS_RMS + r] = sqrtf(ss * (1.0f / DM));
            ((int*)ws)[WS_LAST + r] = last;
        }
    } else {
        const int pb = b - BB;
        const int r = pb >> 6;                 // 64 blocks per row
        // ---- LayerNorm row r into LDS (deterministic, identical per block)
        float f0 = ff[r * DF + tid];
        float f1 = ff[r * DF + tid + 256];
        float mu = block_reduce_sum(f0 + f1, sm) * (1.0f / DF);
        float d0 = f0 - mu, d1 = f1 - mu;
        float var = block_reduce_sum(d0 * d0 + d1 * d1, sm) * (1.0f / DF);
        float inv = rsqrtf(var + LN_EPS);
        hsh[tid]       = d0 * inv * gamma[tid]       + beta[tid];
        hsh[tid + 256] = d1 * inv * gamma[tid + 256] + beta[tid + 256];
        __syncthreads();

        // ---- projection: wave wg handles j = wg*16 .. wg*16+15
        const int wid = tid >> 6, lane = tid & 63;
        const int wg = (pb & 63) * 4 + wid;    // 0..255 within row
        const float4* h4 = (const float4*)hsh;
        const float4 h0 = h4[lane], h1 = h4[lane + 64];
        float ps = 0.0f;
        #pragma unroll 4
        for (int i = 0; i < 16; ++i) {
            const int j = wg * 16 + i;
            const float4* w4 = (const float4*)(W + (size_t)j * DF);  // 128 float4
            float4 w0 = w4[lane], w1 = w4[lane + 64];
            float dot = w0.x * h0.x + w0.y * h0.y + w0.z * h0.z + w0.w * h0.w
                      + w1.x * h1.x + w1.y * h1.y + w1.z * h1.z + w1.w * h1.w;
            for (int off = 32; off > 0; off >>= 1) dot += __shfl_down(dot, off, 64);
            if (lane == 0) {
                float p = dot + bvec[j];
                ws[WS_PROJ + (r << 12) + j] = p;
                ps += p * p;
            }
        }
        if (lane == 0) ws[WS_PSUM + (r << 8) + wg] = ps;
    }
}

// Fused copy + patch (8192 blocks, 2 s-rows / 2048 float4 per block).
// The one block per batch row whose 2 s-rows contain last[r] redundantly
// reduces the 256 |proj|^2 partials to scale[r] itself (no k_scale launch),
// then applies out[r,last,:] = x + proj*scale inline during the copy.
__global__ __launch_bounds__(256) void k_copy(const float* __restrict__ x,
                                              float* __restrict__ out,
                                              const float* __restrict__ ws) {
    __shared__ float sm[4];
    __shared__ float scsh;
    const int b = blockIdx.x, tid = threadIdx.x;
    const int r = b >> 11;                    // 2048 blocks per batch row
    const int s0 = (b & 2047) * 2;            // first s-row of this block
    const int last = ((const int*)ws)[WS_LAST + r];

    if (last >= s0 && last < s0 + 2) {        // block-uniform branch
        float sacc = ws[WS_PSUM + (r << 8) + tid];   // 256 partials, 1/thread
        sacc = block_reduce_sum(sacc, sm);
        if (tid == 0)
            scsh = ws[WS_RMS + r] * SNR / fmaxf(sqrtf(sacc), NORM_EPS);
        __syncthreads();
    }

    const size_t base4 = (size_t)b * 2048;    // float4 index
    const float4* x4 = (const float4*)x;
    float4* o4 = (float4*)out;
    const float4* p4 = (const float4*)(ws + WS_PROJ + (r << 12));
    #pragma unroll 4
    for (int k = 0; k < 8; ++k) {
        const size_t idx = base4 + (size_t)k * 256 + tid;
        float4 v = x4[idx];
        const int s = (int)((idx >> 10) & (SS - 1));   // wave-uniform per iter
        if (s == last) {
            const float sc = scsh;
            float4 p = p4[idx & 1023];
            v.x += p.x * sc;
            v.y += p.y * sc;
            v.z += p.z * sc;
            v.w += p.w * sc;
        }
        o4[idx] = v;
    }
}

extern "C" void kernel_launch(void* const* d_in, const int* in_sizes, int n_in,
                              void* d_out, int out_size, void* d_ws, size_t ws_size,
                              hipStream_t stream) {
    const float* x     = (const float*)d_in[0];
    const float* ff    = (const float*)d_in[1];
    // d_in[2] = token_ids (int64) — unused by reference (trigger_ids empty)
    const int*   mask  = (const int*)d_in[3];
    const float* gamma = (const float*)d_in[4];
    const float* beta  = (const float*)d_in[5];
    const float* W     = (const float*)d_in[6];
    const float* bvec  = (const float*)d_in[7];
    float* out = (float*)d_out;
    float* ws  = (float*)d_ws;

    // A) prep + projection (+ norm partials) in one launch
    k_front<<<260, 256, 0, stream>>>(x, ff, mask, gamma, beta, W, bvec, ws);
    // B) fused bulk copy + hot-row patch (+ inline scale finalize)
    k_copy<<<8192, 256, 0, stream>>>(x, out, ws);
}